// Round 1
// 159.576 us; speedup vs baseline: 1.0131x; 1.0131x over previous
//
#include <hip/hip_runtime.h>

// pixelSNAIL causal attention, MI355X gfx950.
// B=32, N=1024, C=128, CM=256, fp32 in/out.
// softmax over FULL row, strict causal mask, then @V.
// R3: BM=64 (wave owns 16 rows x full CM); AITER-style pipelined staging:
// K double-buffered, issued one tile ahead, partial s_waitcnt vmcnt(4) + raw
// s_barrier so the prefetch stays in flight across the barrier.
// R4: prep_kernel rewritten — all global reads/writes fully coalesced
// (dwordx4), fragment transpose done in LDS with XOR-swizzled slots
// (8 lanes/4-bank-group on every phase = conflict-free). Output layouts
// bit-identical to R3; attn_kernel untouched.

typedef __attribute__((ext_vector_type(8))) short short8;
typedef __attribute__((ext_vector_type(4))) float floatx4;

#define MFMA16(a, b, c) __builtin_amdgcn_mfma_f32_16x16x32_bf16((a), (b), (c), 0, 0, 0)

constexpr int N = 1024, C = 128, CM = 256, BATCH = 32;
constexpr int BM = 64;             // q rows per block (4 waves x 16 rows)
constexpr int BN = 32;             // keys per tile
constexpr int NT = N / BN;         // 32 tiles
constexpr int KFRAG = BN * C;      // 4096 bf16 per K tile (hi or lo)
constexpr int VFRAG = BN * CM;     // 8192 bf16 per V tile
constexpr int PSTR = 40;           // P LDS row stride (bf16): 80 B rows, 16B-aligned b128 reads

__device__ __forceinline__ unsigned short f2bf(float x) {
    unsigned int u = __float_as_uint(x);
    u += 0x7fffu + ((u >> 16) & 1u);   // RNE
    return (unsigned short)(u >> 16);
}
__device__ __forceinline__ float bf2f(unsigned short h) {
    return __uint_as_float(((unsigned int)h) << 16);
}
__device__ __forceinline__ uint4 pack8(const unsigned short* s) {
    uint4 u;
    u.x = (unsigned)s[0] | ((unsigned)s[1] << 16);
    u.y = (unsigned)s[2] | ((unsigned)s[3] << 16);
    u.z = (unsigned)s[4] | ((unsigned)s[5] << 16);
    u.w = (unsigned)s[6] | ((unsigned)s[7] << 16);
    return u;
}
__device__ __forceinline__ uint2 pack4(const unsigned short* s) {
    uint2 u;
    u.x = (unsigned)s[0] | ((unsigned)s[1] << 16);
    u.y = (unsigned)s[2] | ((unsigned)s[3] << 16);
    return u;
}
__device__ __forceinline__ void gl2lds16(const unsigned short* g, unsigned short* l) {
    __builtin_amdgcn_global_load_lds(
        (const __attribute__((address_space(1))) void*)g,
        (__attribute__((address_space(3))) void*)l, 16, 0, 0);
}

// ---------------- prepass: coalesced global IO, LDS transpose ----------------
// Output layouts (consumed by attn_kernel, unchanged from R3):
//  khi/klo chunk ch in [0,512):  rr=ch&15, qq=(ch>>4)&3, ks=(ch>>6)&3, t=ch>>8
//    khb[ch*8+j] = bf16hi(K[n0 + t*16 + rr][ks*32 + qq*8 + j])
//  vf chunk ch in [0,1024):      rr=ch&15, qq=(ch>>4)&3, ct=ch>>6
//    vfb[ch*8+j] = bf16(V[n0 + qq*8 + j][ct*16 + rr])
// Staging puts chunk x at LDS slot x^xor so both the scattered writes and the
// linear output reads hit 8 lanes per 4-bank group (optimal for b64/b128).
__global__ __launch_bounds__(256, 4)
void prep_kernel(const float* __restrict__ kg, const float* __restrict__ vg,
                 unsigned short* __restrict__ khi, unsigned short* __restrict__ klo,
                 unsigned short* __restrict__ vf)
{
    __shared__ __align__(16) unsigned short sKh[KFRAG];   // 8 KB
    __shared__ __align__(16) unsigned short sKl[KFRAG];   // 8 KB
    __shared__ __align__(16) unsigned short sV[VFRAG];    // 16 KB

    const int tid = threadIdx.x;
    const int l = tid & 63, w = tid >> 6;
    const int tile = blockIdx.x, bat = blockIdx.y;
    const int n0 = tile * BN;
    const float* kb = kg + ((size_t)bat * N + n0) * C;
    const float* vb = vg + ((size_t)bat * N + n0) * CM;

    // ---- K staging: contiguous float4 reads (1 KB/instr/wave) ----
    // lin-th float4 = floats [lin*4, lin*4+4) = half of input chunk cr=lin>>1
    // (chunk cr covers K row cr>>4, cols (cr&15)*8..+7).
#pragma unroll
    for (int it = 0; it < 4; ++it) {
        const int lin = tid + it * 256;
        const float4 x = *(const float4*)(kb + (size_t)lin * 4);
        const int cr = lin >> 1, h = lin & 1;
        const int slot = cr ^ ((cr >> 4) & 7);
        float xs[4] = {x.x, x.y, x.z, x.w};
        unsigned short hi[4], lo[4];
#pragma unroll
        for (int e = 0; e < 4; ++e) {
            unsigned short hb = f2bf(xs[e]);
            hi[e] = hb;
            lo[e] = f2bf(xs[e] - bf2f(hb));
        }
        *(uint2*)(&sKh[slot * 8 + h * 4]) = pack4(hi);
        *(uint2*)(&sKl[slot * 8 + h * 4]) = pack4(lo);
    }

    // ---- V staging: 4 contiguous row-segment float4 reads per group ----
    // Wave reads keys k0..k0+3 at cols 4l..4l+3; a lane then owns a 4-key
    // column quad -> one b64 LDS write per col (4 consecutive j of chunk ch).
#pragma unroll
    for (int g = 0; g < 2; ++g) {
        const int k0 = g * 16 + w * 4;
        float xa[4][4];   // [e][d] = V[k0+d][4l+e]
#pragma unroll
        for (int d = 0; d < 4; ++d) {
            const float4 t = *(const float4*)(vb + (size_t)(k0 + d) * CM + l * 4);
            xa[0][d] = t.x; xa[1][d] = t.y; xa[2][d] = t.z; xa[3][d] = t.w;
        }
        const int qq = k0 >> 3, j0 = k0 & 7;
#pragma unroll
        for (int e = 0; e < 4; ++e) {
            const int cm = l * 4 + e;
            const int ct = cm >> 4, rr = cm & 15;
            const int ch = ct * 64 + qq * 16 + rr;
            const int slot = ch ^ ((ch >> 6) & 15);
            unsigned short o[4];
#pragma unroll
            for (int d = 0; d < 4; ++d) o[d] = f2bf(xa[e][d]);
            *(uint2*)(&sV[slot * 8 + j0]) = pack4(o);
        }
    }

    __syncthreads();

    unsigned short* khb = khi + ((size_t)bat * NT + tile) * KFRAG;
    unsigned short* klb = klo + ((size_t)bat * NT + tile) * KFRAG;
    unsigned short* vfb = vf + ((size_t)bat * NT + tile) * VFRAG;

    // ---- K out: linear b128 LDS reads, coalesced 16 B/lane global stores ----
#pragma unroll
    for (int it = 0; it < 2; ++it) {
        const int oc = tid + it * 256;
        // invert ch -> input chunk: row = t*16+rr, cb = ks*4+qq
        const int cr = ((oc & 15) + ((oc >> 8) << 4)) * 16 + ((oc >> 6) & 3) * 4 + ((oc >> 4) & 3);
        const int slot = cr ^ ((cr >> 4) & 7);
        *(uint4*)(khb + (size_t)oc * 8) = *(const uint4*)(&sKh[slot * 8]);
        *(uint4*)(klb + (size_t)oc * 8) = *(const uint4*)(&sKl[slot * 8]);
    }
    // ---- V out ----
#pragma unroll
    for (int it = 0; it < 4; ++it) {
        const int oc = tid + it * 256;
        const int slot = oc ^ ((oc >> 6) & 15);
        *(uint4*)(vfb + (size_t)oc * 8) = *(const uint4*)(&sV[slot * 8]);
    }
}

// ---------------- main attention kernel ----------------
__global__ __launch_bounds__(256, 2)
void attn_kernel(const float* __restrict__ qg, float* __restrict__ og,
                 const unsigned short* __restrict__ khi,
                 const unsigned short* __restrict__ klo,
                 const unsigned short* __restrict__ vf)
{
    __shared__ __align__(16) unsigned short sKhi[2][KFRAG];  // 16 KB dbuf
    __shared__ __align__(16) unsigned short sKlo[2][KFRAG];  // 16 KB dbuf
    __shared__ __align__(16) unsigned short sV[VFRAG];       // 16 KB
    __shared__ __align__(16) unsigned short sP[4 * 16 * PSTR]; // 5 KB

    const int tid = threadIdx.x;
    const int w = tid >> 6, ln = tid & 63;
    const int r = ln & 15, qd = ln >> 4;
    const int bat = blockIdx.x;   // batch on x: linear%8 = bat%8 -> same XCD per batch
    const int qt = blockIdx.y;
    const int q0 = qt * BM;

    const float* qb = qg + (size_t)bat * N * C;
    float* ob = og + (size_t)bat * N * CM;
    const unsigned short* khb = khi + (size_t)bat * NT * KFRAG;
    const unsigned short* klb = klo + (size_t)bat * NT * KFRAG;
    const unsigned short* vfb = vf + (size_t)bat * NT * VFRAG;

    // Q fragments for this wave's 16 rows (q0 + w*16 + r), hi/lo split
    short8 qhi[4], qlo[4];
    {
        const float* qr = qb + (size_t)(q0 + w * 16 + r) * C + qd * 8;
#pragma unroll
        for (int ks = 0; ks < 4; ++ks) {
            float4 a = *(const float4*)(qr + ks * 32);
            float4 b = *(const float4*)(qr + ks * 32 + 4);
            float xs[8] = {a.x, a.y, a.z, a.w, b.x, b.y, b.z, b.w};
            short8 h, l;
#pragma unroll
            for (int j = 0; j < 8; ++j) {
                unsigned short hb = f2bf(xs[j]);
                h[j] = (short)hb;
                l[j] = (short)f2bf(xs[j] - bf2f(hb));
            }
            qhi[ks] = h;
            qlo[ks] = l;
        }
    }

    floatx4 oacc[16];
#pragma unroll
    for (int ct = 0; ct < 16; ++ct) oacc[ct] = (floatx4){0.f, 0.f, 0.f, 0.f};
    float lsum[4] = {0.f, 0.f, 0.f, 0.f};
    const int irow = q0 + w * 16 + qd * 4;
    unsigned short* wP = &sP[w * 16 * PSTR];   // wave-private P buffer

    // prologue: prefetch K tile 0 into buffer 0 (4 loads/thread)
    gl2lds16(khb + (size_t)tid * 8,         &sKhi[0][tid * 8]);
    gl2lds16(khb + (size_t)(tid + 256) * 8, &sKhi[0][(tid + 256) * 8]);
    gl2lds16(klb + (size_t)tid * 8,         &sKlo[0][tid * 8]);
    gl2lds16(klb + (size_t)(tid + 256) * 8, &sKlo[0][(tid + 256) * 8]);

    for (int tile = 0; tile < NT; ++tile) {
        const bool pvt = (tile <= 2 * qt + 1);   // tile holds keys < some row in block
        const int cb = tile & 1;

        // issue V(t) (single-buffered; prior readers cleared by last post-barrier)
        if (pvt) {
            const unsigned short* vs = vfb + (size_t)tile * VFRAG;
#pragma unroll
            for (int i = 0; i < 4; ++i)
                gl2lds16(vs + (size_t)(tid + i * 256) * 8, &sV[(tid + i * 256) * 8]);
        }
        // issue K(t+1) into the other buffer — stays in flight across the barrier
        if (tile + 1 < NT) {
            const unsigned short* k1 = khb + (size_t)(tile + 1) * KFRAG;
            const unsigned short* l1 = klb + (size_t)(tile + 1) * KFRAG;
            unsigned short* dh = &sKhi[cb ^ 1][0];
            unsigned short* dl = &sKlo[cb ^ 1][0];
            gl2lds16(k1 + (size_t)tid * 8,         dh + tid * 8);
            gl2lds16(k1 + (size_t)(tid + 256) * 8, dh + (tid + 256) * 8);
            gl2lds16(l1 + (size_t)tid * 8,         dl + tid * 8);
            gl2lds16(l1 + (size_t)(tid + 256) * 8, dl + (tid + 256) * 8);
            // drain K(t)+V(t); leave the 4 K(t+1) loads in flight
            asm volatile("s_waitcnt vmcnt(4)" ::: "memory");
        } else {
            asm volatile("s_waitcnt vmcnt(0)" ::: "memory");
        }
        asm volatile("s_barrier" ::: "memory");   // all waves' K(t)/V(t) staged

        // ---- QK^T bf16x3, 3 independent chains ----
#pragma unroll
        for (int t = 0; t < 2; ++t) {
            floatx4 a0 = (floatx4){0.f, 0.f, 0.f, 0.f};
            floatx4 a1 = (floatx4){0.f, 0.f, 0.f, 0.f};
            floatx4 a2 = (floatx4){0.f, 0.f, 0.f, 0.f};
#pragma unroll
            for (int ks = 0; ks < 4; ++ks) {
                short8 bh = *(const short8*)(&sKhi[cb][(((t * 4 + ks) * 64) + ln) * 8]);
                short8 bl = *(const short8*)(&sKlo[cb][(((t * 4 + ks) * 64) + ln) * 8]);
                a0 = MFMA16(qhi[ks], bh, a0);
                a1 = MFMA16(qlo[ks], bh, a1);
                a2 = MFMA16(qhi[ks], bl, a2);
            }
            const int jglob = tile * BN + t * 16 + r;
#pragma unroll
            for (int rg = 0; rg < 4; ++rg) {
                float s = a0[rg] + a1[rg] + a2[rg];
                float p = __expf(s - 40.0f);
                lsum[rg] += p;                               // full-row denominator
                if (pvt) {
                    float pm = (jglob < irow + rg) ? p : 0.0f;  // strict causal
                    wP[(qd * 4 + rg) * PSTR + t * 16 + r] = f2bf(pm);
                }
            }
        }

        // ---- PV: wave-private P (one A-frag), full CM=256 per wave ----
        if (pvt) {
            asm volatile("s_waitcnt lgkmcnt(0)" ::: "memory");  // wP writes landed
            short8 ap = *(const short8*)(&wP[r * PSTR + qd * 8]);
#pragma unroll
            for (int ct = 0; ct < 16; ++ct) {
                short8 bv = *(const short8*)(&sV[(ct * 64 + ln) * 8]);
                oacc[ct] = MFMA16(ap, bv, oacc[ct]);
            }
        }
        asm volatile("s_barrier" ::: "memory");   // readers done before next overwrite
    }

    // ---- denominator: reduce across the 16 key-lanes ----
#pragma unroll
    for (int rg = 0; rg < 4; ++rg) {
        float v = lsum[rg];
        v += __shfl_xor(v, 1);
        v += __shfl_xor(v, 2);
        v += __shfl_xor(v, 4);
        v += __shfl_xor(v, 8);
        lsum[rg] = v;
    }

    // ---- divide + store ----
#pragma unroll
    for (int rg = 0; rg < 4; ++rg) {
        float inv = 1.0f / lsum[rg];
        float* orow = ob + (size_t)(q0 + w * 16 + qd * 4 + rg) * CM;
#pragma unroll
        for (int ct = 0; ct < 16; ++ct)
            orow[ct * 16 + r] = oacc[ct][rg] * inv;
    }
}

extern "C" void kernel_launch(void* const* d_in, const int* in_sizes, int n_in,
                              void* d_out, int out_size, void* d_ws, size_t ws_size,
                              hipStream_t stream) {
    const float* q = (const float*)d_in[0];
    const float* k = (const float*)d_in[1];
    const float* v = (const float*)d_in[2];
    float* o = (float*)d_out;
    (void)n_in; (void)in_sizes; (void)out_size; (void)ws_size;

    unsigned short* khi = (unsigned short*)d_ws;                       // 8 MB
    unsigned short* klo = khi + (size_t)BATCH * NT * KFRAG;            // 8 MB
    unsigned short* vf  = klo + (size_t)BATCH * NT * KFRAG;            // 16 MB

    prep_kernel<<<dim3(NT, BATCH), dim3(256), 0, stream>>>(k, v, khi, klo, vf);
    attn_kernel<<<dim3(BATCH, N / BM), dim3(256), 0, stream>>>(q, o, khi, klo, vf);
}

// Round 2
// 151.639 us; speedup vs baseline: 1.0661x; 1.0523x over previous
//
#include <hip/hip_runtime.h>

// pixelSNAIL causal attention, MI355X gfx950.
// B=32, N=1024, C=128, CM=256, fp32 in/out.
// softmax over FULL row, strict causal mask, then @V.
// R3: BM=64 (wave owns 16 rows x full CM); AITER-style pipelined staging.
// R4: prep_kernel: coalesced global IO + LDS transpose (XOR-swizzled slots).
// R5: attn_kernel restructured:
//  - swapped QK^T: mfma(K,Q) -> D[key][qrow]; each lane holds 8 P-values of
//    ONE q-row, so the PV A-frag is built in-register with cvt_pk_bf16 +
//    permlane32/16_swap. P LDS round-trip (8 ds_write_b16 + lgkmcnt(0) +
//    ds_read_b128 per pvt tile) removed entirely; sP freed.
//  - V double-buffered and prefetched one tile ahead with K; steady-state
//    s_waitcnt vmcnt(8) so the barrier never waits on just-issued loads.

typedef __attribute__((ext_vector_type(8))) short short8;
typedef __attribute__((ext_vector_type(4))) float floatx4;

#define MFMA16(a, b, c) __builtin_amdgcn_mfma_f32_16x16x32_bf16((a), (b), (c), 0, 0, 0)

constexpr int N = 1024, C = 128, CM = 256, BATCH = 32;
constexpr int BM = 64;             // q rows per block (4 waves x 16 rows)
constexpr int BN = 32;             // keys per tile
constexpr int NT = N / BN;         // 32 tiles
constexpr int KFRAG = BN * C;      // 4096 bf16 per K tile (hi or lo)
constexpr int VFRAG = BN * CM;     // 8192 bf16 per V tile

__device__ __forceinline__ unsigned short f2bf(float x) {
    unsigned int u = __float_as_uint(x);
    u += 0x7fffu + ((u >> 16) & 1u);   // RNE
    return (unsigned short)(u >> 16);
}
__device__ __forceinline__ float bf2f(unsigned short h) {
    return __uint_as_float(((unsigned int)h) << 16);
}
__device__ __forceinline__ uint2 pack4(const unsigned short* s) {
    uint2 u;
    u.x = (unsigned)s[0] | ((unsigned)s[1] << 16);
    u.y = (unsigned)s[2] | ((unsigned)s[3] << 16);
    return u;
}
__device__ __forceinline__ void gl2lds16(const unsigned short* g, unsigned short* l) {
    __builtin_amdgcn_global_load_lds(
        (const __attribute__((address_space(1))) void*)g,
        (__attribute__((address_space(3))) void*)l, 16, 0, 0);
}

// ---------------- prepass: coalesced global IO, LDS transpose ----------------
// Output layouts (consumed by attn_kernel):
//  khi/klo chunk ch in [0,512):  rr=ch&15, qq=(ch>>4)&3, ks=(ch>>6)&3, t=ch>>8
//    khb[ch*8+j] = bf16hi(K[n0 + t*16 + rr][ks*32 + qq*8 + j])
//  vf chunk ch in [0,1024):      rr=ch&15, qq=(ch>>4)&3, ct=ch>>6
//    vfb[ch*8+j] = bf16(V[n0 + qq*8 + j][ct*16 + rr])
__global__ __launch_bounds__(256, 4)
void prep_kernel(const float* __restrict__ kg, const float* __restrict__ vg,
                 unsigned short* __restrict__ khi, unsigned short* __restrict__ klo,
                 unsigned short* __restrict__ vf)
{
    __shared__ __align__(16) unsigned short sKh[KFRAG];   // 8 KB
    __shared__ __align__(16) unsigned short sKl[KFRAG];   // 8 KB
    __shared__ __align__(16) unsigned short sV[VFRAG];    // 16 KB

    const int tid = threadIdx.x;
    const int l = tid & 63, w = tid >> 6;
    const int tile = blockIdx.x, bat = blockIdx.y;
    const int n0 = tile * BN;
    const float* kb = kg + ((size_t)bat * N + n0) * C;
    const float* vb = vg + ((size_t)bat * N + n0) * CM;

    // ---- K staging: contiguous float4 reads (1 KB/instr/wave) ----
#pragma unroll
    for (int it = 0; it < 4; ++it) {
        const int lin = tid + it * 256;
        const float4 x = *(const float4*)(kb + (size_t)lin * 4);
        const int cr = lin >> 1, h = lin & 1;
        const int slot = cr ^ ((cr >> 4) & 7);
        float xs[4] = {x.x, x.y, x.z, x.w};
        unsigned short hi[4], lo[4];
#pragma unroll
        for (int e = 0; e < 4; ++e) {
            unsigned short hb = f2bf(xs[e]);
            hi[e] = hb;
            lo[e] = f2bf(xs[e] - bf2f(hb));
        }
        *(uint2*)(&sKh[slot * 8 + h * 4]) = pack4(hi);
        *(uint2*)(&sKl[slot * 8 + h * 4]) = pack4(lo);
    }

    // ---- V staging: 4 contiguous row-segment float4 reads per group ----
#pragma unroll
    for (int g = 0; g < 2; ++g) {
        const int k0 = g * 16 + w * 4;
        float xa[4][4];   // [e][d] = V[k0+d][4l+e]
#pragma unroll
        for (int d = 0; d < 4; ++d) {
            const float4 t = *(const float4*)(vb + (size_t)(k0 + d) * CM + l * 4);
            xa[0][d] = t.x; xa[1][d] = t.y; xa[2][d] = t.z; xa[3][d] = t.w;
        }
        const int qq = k0 >> 3, j0 = k0 & 7;
#pragma unroll
        for (int e = 0; e < 4; ++e) {
            const int cm = l * 4 + e;
            const int ct = cm >> 4, rr = cm & 15;
            const int ch = ct * 64 + qq * 16 + rr;
            const int slot = ch ^ ((ch >> 6) & 15);
            unsigned short o[4];
#pragma unroll
            for (int d = 0; d < 4; ++d) o[d] = f2bf(xa[e][d]);
            *(uint2*)(&sV[slot * 8 + j0]) = pack4(o);
        }
    }

    __syncthreads();

    unsigned short* khb = khi + ((size_t)bat * NT + tile) * KFRAG;
    unsigned short* klb = klo + ((size_t)bat * NT + tile) * KFRAG;
    unsigned short* vfb = vf + ((size_t)bat * NT + tile) * VFRAG;

    // ---- K out: linear b128 LDS reads, coalesced 16 B/lane global stores ----
#pragma unroll
    for (int it = 0; it < 2; ++it) {
        const int oc = tid + it * 256;
        const int cr = ((oc & 15) + ((oc >> 8) << 4)) * 16 + ((oc >> 6) & 3) * 4 + ((oc >> 4) & 3);
        const int slot = cr ^ ((cr >> 4) & 7);
        *(uint4*)(khb + (size_t)oc * 8) = *(const uint4*)(&sKh[slot * 8]);
        *(uint4*)(klb + (size_t)oc * 8) = *(const uint4*)(&sKl[slot * 8]);
    }
    // ---- V out ----
#pragma unroll
    for (int it = 0; it < 4; ++it) {
        const int oc = tid + it * 256;
        const int slot = oc ^ ((oc >> 6) & 15);
        *(uint4*)(vfb + (size_t)oc * 8) = *(const uint4*)(&sV[slot * 8]);
    }
}

// ---------------- main attention kernel ----------------
__global__ __launch_bounds__(256, 2)
void attn_kernel(const float* __restrict__ qg, float* __restrict__ og,
                 const unsigned short* __restrict__ khi,
                 const unsigned short* __restrict__ klo,
                 const unsigned short* __restrict__ vf)
{
    __shared__ __align__(16) unsigned short sKhi[2][KFRAG];  // 16 KB dbuf
    __shared__ __align__(16) unsigned short sKlo[2][KFRAG];  // 16 KB dbuf
    __shared__ __align__(16) unsigned short sV[2][VFRAG];    // 32 KB dbuf

    const int tid = threadIdx.x;
    const int w = tid >> 6, ln = tid & 63;
    const int r = ln & 15, qd = ln >> 4;
    const int bat = blockIdx.x;   // batch on x: linear%8 = bat%8 -> same XCD per batch
    const int qt = blockIdx.y;
    const int q0 = qt * BM;

    const float* qb = qg + (size_t)bat * N * C;
    float* ob = og + (size_t)bat * N * CM;
    const unsigned short* khb = khi + (size_t)bat * NT * KFRAG;
    const unsigned short* klb = klo + (size_t)bat * NT * KFRAG;
    const unsigned short* vfb = vf + (size_t)bat * NT * VFRAG;

    // Q fragments for this wave's 16 rows (q0 + w*16 + r), hi/lo split
    short8 qhi[4], qlo[4];
    {
        const float* qr = qb + (size_t)(q0 + w * 16 + r) * C + qd * 8;
#pragma unroll
        for (int ks = 0; ks < 4; ++ks) {
            float4 a = *(const float4*)(qr + ks * 32);
            float4 b = *(const float4*)(qr + ks * 32 + 4);
            float xs[8] = {a.x, a.y, a.z, a.w, b.x, b.y, b.z, b.w};
            short8 h, l;
#pragma unroll
            for (int j = 0; j < 8; ++j) {
                unsigned short hb = f2bf(xs[j]);
                h[j] = (short)hb;
                l[j] = (short)f2bf(xs[j] - bf2f(hb));
            }
            qhi[ks] = h;
            qlo[ks] = l;
        }
    }

    floatx4 oacc[16];
#pragma unroll
    for (int ct = 0; ct < 16; ++ct) oacc[ct] = (floatx4){0.f, 0.f, 0.f, 0.f};
    float lsum = 0.f;                       // this lane's q-row (= r) partial denom
    const int qrow = q0 + w * 16 + r;       // swapped-QK^T: lane owns ONE q-row

    // prologue: prefetch K(0) + V(0) into buffer 0 (8 loads/thread)
    gl2lds16(khb + (size_t)tid * 8,         &sKhi[0][tid * 8]);
    gl2lds16(khb + (size_t)(tid + 256) * 8, &sKhi[0][(tid + 256) * 8]);
    gl2lds16(klb + (size_t)tid * 8,         &sKlo[0][tid * 8]);
    gl2lds16(klb + (size_t)(tid + 256) * 8, &sKlo[0][(tid + 256) * 8]);
#pragma unroll
    for (int i = 0; i < 4; ++i)
        gl2lds16(vfb + (size_t)(tid + i * 256) * 8, &sV[0][(tid + i * 256) * 8]);

    for (int tile = 0; tile < NT; ++tile) {
        const bool pvt = (tile <= 2 * qt + 1);   // tile holds keys < some row in block
        const int cb = tile & 1;

        // prefetch K(t+1) (+ V(t+1) if needed) into the other buffers; the
        // counted vmcnt leaves exactly the just-issued loads in flight.
        if (tile + 1 < NT) {
            const unsigned short* k1 = khb + (size_t)(tile + 1) * KFRAG;
            const unsigned short* l1 = klb + (size_t)(tile + 1) * KFRAG;
            unsigned short* dh = &sKhi[cb ^ 1][0];
            unsigned short* dl = &sKlo[cb ^ 1][0];
            gl2lds16(k1 + (size_t)tid * 8,         dh + tid * 8);
            gl2lds16(k1 + (size_t)(tid + 256) * 8, dh + (tid + 256) * 8);
            gl2lds16(l1 + (size_t)tid * 8,         dl + tid * 8);
            gl2lds16(l1 + (size_t)(tid + 256) * 8, dl + (tid + 256) * 8);
            if (tile + 1 <= 2 * qt + 1) {        // V(t+1) needed
                const unsigned short* vs = vfb + (size_t)(tile + 1) * VFRAG;
                unsigned short* dv = &sV[cb ^ 1][0];
#pragma unroll
                for (int i = 0; i < 4; ++i)
                    gl2lds16(vs + (size_t)(tid + i * 256) * 8, dv + (tid + i * 256) * 8);
                asm volatile("s_waitcnt vmcnt(8)" ::: "memory");   // drain K(t)+V(t)
            } else {
                asm volatile("s_waitcnt vmcnt(4)" ::: "memory");   // drain K(t)(+V(t))
            }
        } else {
            asm volatile("s_waitcnt vmcnt(0)" ::: "memory");
        }
        asm volatile("s_barrier" ::: "memory");   // all waves' K(t)/V(t) staged

        // ---- swapped QK^T bf16x3: D[key][qrow], 3 independent chains ----
        float pk[8];
#pragma unroll
        for (int t = 0; t < 2; ++t) {
            floatx4 a0 = (floatx4){0.f, 0.f, 0.f, 0.f};
            floatx4 a1 = (floatx4){0.f, 0.f, 0.f, 0.f};
            floatx4 a2 = (floatx4){0.f, 0.f, 0.f, 0.f};
#pragma unroll
            for (int ks = 0; ks < 4; ++ks) {
                short8 bh = *(const short8*)(&sKhi[cb][(((t * 4 + ks) * 64) + ln) * 8]);
                short8 bl = *(const short8*)(&sKlo[cb][(((t * 4 + ks) * 64) + ln) * 8]);
                a0 = MFMA16(bh, qhi[ks], a0);     // A=K -> rows=keys, cols=qrows
                a1 = MFMA16(bh, qlo[ks], a1);
                a2 = MFMA16(bl, qhi[ks], a2);
            }
            const int kbase = tile * BN + t * 16 + qd * 4;
#pragma unroll
            for (int rg = 0; rg < 4; ++rg) {
                float s = a0[rg] + a1[rg] + a2[rg];
                float p = __expf(s - 40.0f);
                lsum += p;                                  // full-row denominator
                pk[t * 4 + rg] = (kbase + rg < qrow) ? p : 0.0f;  // strict causal
            }
        }

        // ---- PV: P->A-frag built in-register (cvt_pk + permlane swaps) ----
        if (pvt) {
            // w0..w3 = packed bf16 pairs: (t0 k0,k1)(t0 k2,k3)(t1 k0,k1)(t1 k2,k3)
            unsigned int w0, w1, w2, w3;
            asm("v_cvt_pk_bf16_f32 %0, %1, %2" : "=v"(w0) : "v"(pk[0]), "v"(pk[1]));
            asm("v_cvt_pk_bf16_f32 %0, %1, %2" : "=v"(w1) : "v"(pk[2]), "v"(pk[3]));
            asm("v_cvt_pk_bf16_f32 %0, %1, %2" : "=v"(w2) : "v"(pk[4]), "v"(pk[5]));
            asm("v_cvt_pk_bf16_f32 %0, %1, %2" : "=v"(w3) : "v"(pk[6]), "v"(pk[7]));
            // lane group qd needs keys 8qd..8qd+7 of its row r:
            // (o0,o2) = permlane16_swap(permlane32_swap(w0, w2)); same for (w1,w3).
            asm("v_permlane32_swap_b32 %0, %1" : "+v"(w0), "+v"(w2));
            asm("v_permlane16_swap_b32 %0, %1" : "+v"(w0), "+v"(w2));
            asm("v_permlane32_swap_b32 %0, %1" : "+v"(w1), "+v"(w3));
            asm("v_permlane16_swap_b32 %0, %1" : "+v"(w1), "+v"(w3));
            uint4 apu = make_uint4(w0, w1, w2, w3);   // keys (0,1)(2,3)(4,5)(6,7)+8qd
            short8 ap = *(const short8*)&apu;
#pragma unroll
            for (int ct = 0; ct < 16; ++ct) {
                short8 bv = *(const short8*)(&sV[cb][(ct * 64 + ln) * 8]);
                oacc[ct] = MFMA16(ap, bv, oacc[ct]);
            }
        }
        asm volatile("s_barrier" ::: "memory");   // readers done before next overwrite
    }

    // ---- denominator: reduce across the 4 qd groups (lane owns row r) ----
    float vtot = lsum;
    vtot += __shfl_xor(vtot, 16);
    vtot += __shfl_xor(vtot, 32);
    // vtot = full denom for row (q0 + w*16 + r) on every lane

    // ---- divide + store (oacc rows are qd*4+rg; fetch matching denom) ----
#pragma unroll
    for (int rg = 0; rg < 4; ++rg) {
        float inv = 1.0f / __shfl(vtot, qd * 4 + rg);   // lane qd*4+rg has row qd*4+rg
        float* orow = ob + (size_t)(q0 + w * 16 + qd * 4 + rg) * CM;
#pragma unroll
        for (int ct = 0; ct < 16; ++ct)
            orow[ct * 16 + r] = oacc[ct][rg] * inv;
    }
}

extern "C" void kernel_launch(void* const* d_in, const int* in_sizes, int n_in,
                              void* d_out, int out_size, void* d_ws, size_t ws_size,
                              hipStream_t stream) {
    const float* q = (const float*)d_in[0];
    const float* k = (const float*)d_in[1];
    const float* v = (const float*)d_in[2];
    float* o = (float*)d_out;
    (void)n_in; (void)in_sizes; (void)out_size; (void)ws_size;

    unsigned short* khi = (unsigned short*)d_ws;                       // 8 MB
    unsigned short* klo = khi + (size_t)BATCH * NT * KFRAG;            // 8 MB
    unsigned short* vf  = klo + (size_t)BATCH * NT * KFRAG;            // 16 MB

    prep_kernel<<<dim3(NT, BATCH), dim3(256), 0, stream>>>(k, v, khi, klo, vf);
    attn_kernel<<<dim3(BATCH, N / BM), dim3(256), 0, stream>>>(q, o, khi, klo, vf);
}